// Round 6
// baseline (227.592 us; speedup 1.0000x reference)
//
#include <hip/hip_runtime.h>
#include <hip/hip_bf16.h>
#include <stdint.h>

#define M_POS 0.5f
#define M_NEG 0.1f
#define LAM_NEG 1.0f

typedef __attribute__((ext_vector_type(16))) float floatx16;  // 32x32 MFMA accumulator
typedef __attribute__((ext_vector_type(8)))  int   intx8;     // 32B fp8 MFMA operand

union Frag { intx8 v; int4 q[2]; };

// ---------------- Kernel A: row sumsq, inv_norm, fp32 -> fp8(e4m3) quantize, zero accs ----
__global__ __launch_bounds__(256) void prep_kernel(
    const float* __restrict__ cb, unsigned char* __restrict__ cb_q,
    float* __restrict__ sq, float* __restrict__ inv_norm,
    unsigned* __restrict__ zero_base, int zero_len,
    int N, int d)
{
    const int gi = blockIdx.x * 256 + threadIdx.x;
    if (gi < zero_len) zero_base[gi] = 0u;

    const int row = blockIdx.x;
    const float* src = cb + (size_t)row * d;
    unsigned char* dst = cb_q + (size_t)row * d;
    const int t = threadIdx.x;

    float s = 0.f;
    for (int c = t * 4; c < d; c += 1024) {
        float4 v = *(const float4*)(src + c);
        s += v.x * v.x + v.y * v.y + v.z * v.z + v.w * v.w;
        int pk = __builtin_amdgcn_cvt_pk_fp8_f32(v.x, v.y, 0, false);   // bytes 0,1
        pk     = __builtin_amdgcn_cvt_pk_fp8_f32(v.z, v.w, pk, true);   // bytes 2,3
        *(int*)(dst + c) = pk;
    }
    for (int o = 32; o > 0; o >>= 1) s += __shfl_down(s, o, 64);
    __shared__ float wsum[4];
    if ((t & 63) == 0) wsum[t >> 6] = s;
    __syncthreads();
    if (t == 0) {
        float tot = wsum[0] + wsum[1] + wsum[2] + wsum[3];
        sq[row] = tot;
        inv_norm[row] = rsqrtf(tot);
    }
}

// ---------------- Kernel B: fused symmetric fp8 Gram GEMM (MX 32x32x64) + loss epilogue ----
// Upper-triangular 128x128 tiles. Inner loop: v_mfma_scale_f32_32x32x64_f8f6f4 with unit
// E8M0 scales (127 = 2^0) — bit-identical math to non-scaled fp8 at 2x the MFMA rate.
// Per wave: 64x64 = 2x2 tiles of 32x32, 4 MFMA per K=64 step. C/D layout (m74/m101):
// col=lane&31, row=(reg&3)+8*(reg>>2)+4*(lane>>5). LDS: 64B rows, 16B chunk q of row r
// stores logical chunk q^((r>>1)&3); fragment ds_read_b128 hits the 8-words/bank floor.
__global__ __launch_bounds__(256) void gram_loss_kernel(
    const unsigned char* __restrict__ A,   // N x d fp8
    const float* __restrict__ sq, const float* __restrict__ inv_norm,
    const int* __restrict__ starts, const int* __restrict__ ends,
    const int* __restrict__ max_ip,
    float* __restrict__ pos_acc, float* __restrict__ neg_acc,
    int N, int d)
{
    const int M = min(N, max_ip[0] + 1);

    // triangular decode: blockIdx.x -> (by, bx), by <= bx
    const int t = blockIdx.x;
    int bx = (int)((sqrtf(8.f * (float)t + 1.f) - 1.f) * 0.5f);
    while ((bx + 1) * (bx + 2) / 2 <= t) bx++;
    while (bx * (bx + 1) / 2 > t) bx--;
    const int by = t - bx * (bx + 1) / 2;

    const int rowBase = by * 128;
    const int colBase = bx * 128;
    const bool isDiag = (by == bx);

    __shared__ alignas(16) unsigned char ldsA[128 * 64];
    __shared__ alignas(16) unsigned char ldsB[128 * 64];

    const int tid  = threadIdx.x;
    const int wave = tid >> 6;
    const int lane = tid & 63;
    const int wr = (wave >> 1) * 64;
    const int wc = (wave & 1) * 64;

    floatx16 acc[2][2];
#pragma unroll
    for (int a = 0; a < 2; ++a)
#pragma unroll
        for (int b = 0; b < 2; ++b)
#pragma unroll
            for (int e = 0; e < 16; ++e) acc[a][b][e] = 0.f;

    // staging: 16 rows x 4 chunks per wave-issue; dst = base + lane*16 (lane-linear).
    const int sR = lane >> 2;                       // local row 0..15
    const int sQ = lane & 3;                        // 16B chunk 0..3
    const int kTiles = d / 64;

    // fragment-read constants (32x32 operand: row = base + cl, k-half = h)
    const int cl = lane & 31;
    const int h  = lane >> 5;
    const int rowx = (cl >> 1) & 3;                 // bases are multiples of 32 -> no effect
    const int c0 = (((2 * h)     ^ rowx) * 16);
    const int c1 = (((2 * h + 1) ^ rowx) * 16);

    for (int kt = 0; kt < kTiles; ++kt) {
        __syncthreads();
        const int k0 = kt * 64;
#pragma unroll
        for (int hh = 0; hh < 2; ++hh) {
            const int r = wave * 32 + hh * 16 + sR;              // tile row 0..127
            const int srcQ = sQ ^ ((r >> 1) & 3);
            const unsigned char* ga = A + (size_t)(rowBase + r) * d + k0 + srcQ * 16;
            const unsigned char* gb = A + (size_t)(colBase + r) * d + k0 + srcQ * 16;
            __builtin_amdgcn_global_load_lds(
                (const __attribute__((address_space(1))) void*)ga,
                (__attribute__((address_space(3))) void*)(ldsA + r * 64 + sQ * 16), 16, 0, 0);
            __builtin_amdgcn_global_load_lds(
                (const __attribute__((address_space(1))) void*)gb,
                (__attribute__((address_space(3))) void*)(ldsB + r * 64 + sQ * 16), 16, 0, 0);
        }
        __syncthreads();

        Frag fa[2], fb[2];
#pragma unroll
        for (int rt = 0; rt < 2; ++rt) {
            const unsigned char* pa = ldsA + (wr + rt * 32 + cl) * 64;
            fa[rt].q[0] = *(const int4*)(pa + c0);
            fa[rt].q[1] = *(const int4*)(pa + c1);
            const unsigned char* pb = ldsB + (wc + rt * 32 + cl) * 64;
            fb[rt].q[0] = *(const int4*)(pb + c0);
            fb[rt].q[1] = *(const int4*)(pb + c1);
        }
#pragma unroll
        for (int rt = 0; rt < 2; ++rt)
#pragma unroll
            for (int ct = 0; ct < 2; ++ct)
                acc[rt][ct] = __builtin_amdgcn_mfma_scale_f32_32x32x64_f8f6f4(
                    fa[rt].v, fb[ct].v, acc[rt][ct], 0, 0, 0, 127, 0, 127);
    }

    // ---- epilogue (32x32 C/D layout: col=lane&31, row=(reg&3)+8*(reg>>2)+4*h) ----
    const int jlo = colBase + wc;
    const int ilo = rowBase + wr;

    int   jn2[2];
    float jinv2[2];
    bool  jv2[2];
#pragma unroll
    for (int ct = 0; ct < 2; ++ct) {
        const int j = jlo + ct * 32 + cl;
        jn2[ct]  = j;
        jinv2[ct] = inv_norm[j];
        jv2[ct] = (j < M);
    }

    // wave-uniform positive-pair possibility check
    bool posLane = false;
    {
        const int ri = ilo + lane;
        if (ri < M) posLane |= (ends[ri] >= jlo) && (starts[ri] <= jlo + 63);
        if (!isDiag) {
            const int cj = jlo + lane;
            if (cj < M) posLane |= (ends[cj] >= ilo) && (starts[cj] <= ilo + 63);
        }
    }
    const bool fullPath = (__ballot(posLane) != 0ULL);

    float posc[2] = {0.f, 0.f};
    float negc[2] = {0.f, 0.f};

    if (fullPath) {
        int   jns2[2], jne2[2];
        float jsq2[2];
#pragma unroll
        for (int ct = 0; ct < 2; ++ct) {
            jsq2[ct] = sq[jn2[ct]];
            jns2[ct] = jv2[ct] ? starts[jn2[ct]] : 0;
            jne2[ct] = jv2[ct] ? ends[jn2[ct]]   : -1;
        }
#pragma unroll
        for (int rt = 0; rt < 2; ++rt) {
#pragma unroll
            for (int reg = 0; reg < 16; ++reg) {
                const int rowIn = (reg & 3) + 8 * (reg >> 2) + 4 * h;
                const int i = ilo + rt * 32 + rowIn;
                const bool rowValid = (i < M);
                const int ns = rowValid ? starts[i] : 0;
                const int ne = rowValid ? ends[i]   : -1;
                const float iinv = inv_norm[i];
                const float isq  = sq[i];
                float posp = 0.f, negp = 0.f;
#pragma unroll
                for (int ct = 0; ct < 2; ++ct) {
                    const float dot = acc[rt][ct][reg];
                    const int j = jn2[ct];
                    float cosv = dot * iinv * jinv2[ct];
                    cosv = fminf(fmaxf(cosv, -1.f), 1.f);
                    float tn = fmaxf(fabsf(cosv) - M_NEG, 0.f);
                    const float nterm = tn * tn;
                    const float d2 = fmaxf(isq + jsq2[ct] - 2.f * dot, 0.f);
                    float tp = fmaxf(sqrtf(d2) - M_POS, 0.f);
                    const float pterm = tp * tp;
                    const bool dg = (j == i);
                    if (rowValid) {
                        const bool in_r = (j >= ns) && (j <= ne);
                        if (in_r && !dg) posp += pterm;
                        if (!in_r || dg) negp += nterm;
                    }
                    if (!isDiag && jv2[ct]) {
                        const bool in_c = (i >= jns2[ct]) && (i <= jne2[ct]);
                        if (in_c && !dg) posc[ct] += pterm;
                        if (!in_c || dg) negc[ct] += nterm;
                    }
                }
                // reduce over the 32 column-lanes of this row (bit5 = h untouched)
#pragma unroll
                for (int m = 1; m < 32; m <<= 1) {
                    posp += __shfl_xor(posp, m, 64);
                    negp += __shfl_xor(negp, m, 64);
                }
                if (rowValid && cl == 0) {
                    atomicAdd(&pos_acc[i], posp);
                    atomicAdd(&neg_acc[i], negp);
                }
            }
        }
        if (!isDiag) {
#pragma unroll
            for (int ct = 0; ct < 2; ++ct) {
                posc[ct] += __shfl_xor(posc[ct], 32, 64);
                negc[ct] += __shfl_xor(negc[ct], 32, 64);
            }
            if (h == 0) {
#pragma unroll
                for (int ct = 0; ct < 2; ++ct) {
                    if (jv2[ct]) {
                        atomicAdd(&pos_acc[jn2[ct]], posc[ct]);
                        atomicAdd(&neg_acc[jn2[ct]], negc[ct]);
                    }
                }
            }
        }
    } else {
        // fast path: every element is a negative for both its row and its column
#pragma unroll
        for (int rt = 0; rt < 2; ++rt) {
#pragma unroll
            for (int reg = 0; reg < 16; ++reg) {
                const int rowIn = (reg & 3) + 8 * (reg >> 2) + 4 * h;
                const int i = ilo + rt * 32 + rowIn;
                const float iinv = inv_norm[i];
                float negp = 0.f;
#pragma unroll
                for (int ct = 0; ct < 2; ++ct) {
                    const float dot = acc[rt][ct][reg];
                    float cosv = dot * iinv * jinv2[ct];
                    cosv = fminf(fmaxf(cosv, -1.f), 1.f);
                    float tn = fmaxf(fabsf(cosv) - M_NEG, 0.f);
                    const float nterm = tn * tn;
                    negp += nterm;
                    negc[ct] += nterm;
                }
#pragma unroll
                for (int m = 1; m < 32; m <<= 1)
                    negp += __shfl_xor(negp, m, 64);
                if ((i < M) && cl == 0)
                    atomicAdd(&neg_acc[i], negp);
            }
        }
        if (!isDiag) {
#pragma unroll
            for (int ct = 0; ct < 2; ++ct)
                negc[ct] += __shfl_xor(negc[ct], 32, 64);
            if (h == 0) {
#pragma unroll
                for (int ct = 0; ct < 2; ++ct)
                    if (jv2[ct])
                        atomicAdd(&neg_acc[jn2[ct]], negc[ct]);
            }
        }
    }
}

// ---------------- Kernel C: per-row normalize + global mean ----------------
__global__ __launch_bounds__(1024) void finalize_kernel(
    const float* __restrict__ pos_acc, const float* __restrict__ neg_acc,
    const int* __restrict__ starts, const int* __restrict__ ends,
    const int* __restrict__ max_ip, int N, float* __restrict__ out)
{
    const int M = min(N, max_ip[0] + 1);
    const int t = threadIdx.x;
    float total = 0.f;
    int cnt = 0;
    for (int i = t; i < M; i += blockDim.x) {
        const int ns = starts[i], ne = ends[i];
        const int lo = max(ns, 0), hi = min(ne, N - 1);
        const int inr = max(hi - lo + 1, 0);
        const bool dg = (i >= ns) && (i <= ne);
        const int pos_cnt = inr - (dg ? 1 : 0);
        const int neg_cnt = N - inr + (dg ? 1 : 0);
        if (pos_cnt > 0 && neg_cnt > 0) {
            total += pos_acc[i] / (float)max(pos_cnt, 1)
                   + LAM_NEG * neg_acc[i] / (float)max(neg_cnt, 1);
            cnt++;
        }
    }
    for (int o = 32; o > 0; o >>= 1) {
        total += __shfl_down(total, o, 64);
        cnt   += __shfl_down(cnt, o, 64);
    }
    __shared__ float ts[16];
    __shared__ int   cs[16];
    const int w = t >> 6;
    if ((t & 63) == 0) { ts[w] = total; cs[w] = cnt; }
    __syncthreads();
    if (t == 0) {
        float T = 0.f; int C = 0;
        const int nw = blockDim.x >> 6;
        for (int i = 0; i < nw; ++i) { T += ts[i]; C += cs[i]; }
        out[0] = (C > 0) ? T / (float)C : 0.f;
    }
}

extern "C" void kernel_launch(void* const* d_in, const int* in_sizes, int n_in,
                              void* d_out, int out_size, void* d_ws, size_t ws_size,
                              hipStream_t stream) {
    const float* cb     = (const float*)d_in[0];
    const int*   starts = (const int*)d_in[1];
    const int*   ends   = (const int*)d_in[2];
    const int*   max_ip = (const int*)d_in[3];
    float* out = (float*)d_out;

    const int N = in_sizes[1];
    const int d = in_sizes[0] / N;

    char* ws = (char*)d_ws;
    unsigned char* cb_q = (unsigned char*)ws;
    size_t off = ((size_t)N * d + 255) & ~(size_t)255;
    float* sq       = (float*)(ws + off); off += (size_t)N * 4;
    float* inv_norm = (float*)(ws + off); off += (size_t)N * 4;
    float* pos_acc  = (float*)(ws + off); off += (size_t)N * 4;
    float* neg_acc  = (float*)(ws + off); off += (size_t)N * 4;

    // prep zeroes pos_acc/neg_acc (2N u32)
    prep_kernel<<<N, 256, 0, stream>>>(cb, cb_q, sq, inv_norm,
                                       (unsigned*)pos_acc, 2 * N, N, d);

    const int nb = N / 128;
    const int nBlocks = nb * (nb + 1) / 2;   // upper-triangular tiles
    gram_loss_kernel<<<nBlocks, 256, 0, stream>>>(cb_q, sq, inv_norm, starts, ends,
                                                  max_ip, pos_acc, neg_acc, N, d);

    finalize_kernel<<<1, 1024, 0, stream>>>(pos_acc, neg_acc, starts, ends, max_ip, N, out);
}

// Round 7
// 213.015 us; speedup vs baseline: 1.0684x; 1.0684x over previous
//
#include <hip/hip_runtime.h>
#include <hip/hip_bf16.h>
#include <stdint.h>

#define M_POS 0.5f
#define M_NEG 0.1f
#define LAM_NEG 1.0f

typedef __attribute__((ext_vector_type(4))) float floatx4;  // MFMA accumulator
using f8x8 = long;   // 8 fp8 bytes = 2 VGPRs (fp8 16x16x32 MFMA operand)

// ---------------- Kernel A: row sumsq, inv_norm, fp32 -> fp8(e4m3) quantize, zero accs ----
__global__ __launch_bounds__(256) void prep_kernel(
    const float* __restrict__ cb, unsigned char* __restrict__ cb_q,
    float* __restrict__ sq, float* __restrict__ inv_norm,
    unsigned* __restrict__ zero_base, int zero_len,
    int N, int d)
{
    const int gi = blockIdx.x * 256 + threadIdx.x;
    if (gi < zero_len) zero_base[gi] = 0u;

    const int row = blockIdx.x;
    const float* src = cb + (size_t)row * d;
    unsigned char* dst = cb_q + (size_t)row * d;
    const int t = threadIdx.x;

    float s = 0.f;
    for (int c = t * 4; c < d; c += 1024) {
        float4 v = *(const float4*)(src + c);
        s += v.x * v.x + v.y * v.y + v.z * v.z + v.w * v.w;
        int pk = __builtin_amdgcn_cvt_pk_fp8_f32(v.x, v.y, 0, false);   // bytes 0,1
        pk     = __builtin_amdgcn_cvt_pk_fp8_f32(v.z, v.w, pk, true);   // bytes 2,3
        *(int*)(dst + c) = pk;
    }
    for (int o = 32; o > 0; o >>= 1) s += __shfl_down(s, o, 64);
    __shared__ float wsum[4];
    if ((t & 63) == 0) wsum[t >> 6] = s;
    __syncthreads();
    if (t == 0) {
        float tot = wsum[0] + wsum[1] + wsum[2] + wsum[3];
        sq[row] = tot;
        inv_norm[row] = rsqrtf(tot);
    }
}

// ---------------- Kernel B: fused symmetric fp8 Gram GEMM + loss epilogue + finalize ------
// R5 structure (16x16x32 fp8 — best measured) with BK=128: 8 K-tiles, 16 barriers (was 32).
// LDS rows 128 B; physical 16B chunk p of row r holds logical chunk p^(r&7) -> fragment
// ds_read_b64 lands at the 4-words/bank floor. Last block runs the finalize inline:
// fence+counter by tid0 ONLY (R3's per-thread fences were the regression).
__global__ __launch_bounds__(256, 3) void gram_loss_kernel(
    const unsigned char* __restrict__ A,   // N x d fp8
    const float* __restrict__ sq, const float* __restrict__ inv_norm,
    const int* __restrict__ starts, const int* __restrict__ ends,
    const int* __restrict__ max_ip,
    float* __restrict__ pos_acc, float* __restrict__ neg_acc,
    unsigned* __restrict__ counter, float* __restrict__ out,
    int N, int d)
{
    const int M = min(N, max_ip[0] + 1);

    // triangular decode: blockIdx.x -> (by, bx), by <= bx
    const int t = blockIdx.x;
    int bx = (int)((sqrtf(8.f * (float)t + 1.f) - 1.f) * 0.5f);
    while ((bx + 1) * (bx + 2) / 2 <= t) bx++;
    while (bx * (bx + 1) / 2 > t) bx--;
    const int by = t - bx * (bx + 1) / 2;

    const int rowBase = by * 128;
    const int colBase = bx * 128;
    const bool isDiag = (by == bx);

    __shared__ alignas(16) unsigned char ldsA[128 * 128];
    __shared__ alignas(16) unsigned char ldsB[128 * 128];

    const int tid  = threadIdx.x;
    const int wave = tid >> 6;
    const int lane = tid & 63;
    const int wr = (wave >> 1) * 64;
    const int wc = (wave & 1) * 64;

    floatx4 acc[4][4];
#pragma unroll
    for (int a = 0; a < 4; ++a)
#pragma unroll
        for (int b = 0; b < 4; ++b) acc[a][b] = (floatx4){0.f, 0.f, 0.f, 0.f};

    // staging: per issue, 8 rows x 8 chunks (1 KB contiguous LDS); dst lane-linear.
    // srcQ xor is lane-constant: r&7 == lane>>3 for all h/kt.
    const int sRow = lane >> 3;                         // 0..7
    const int sChk = lane & 7;                          // 16B chunk 0..7
    const int srcOffC = ((sChk ^ sRow) * 16);           // logical chunk fetched
    const int kTiles = d / 128;                         // 8

    // fragment-read constants
    const int rl = lane & 15;
    const int g  = lane >> 4;       // 0..3
    const int fragOddB = (g & 1) * 8;
    const int fragChkBase = g >> 1;                     // logical chunk = 2*ko + (g>>1)
    const int rx = rl & 7;

    for (int kt = 0; kt < kTiles; ++kt) {
        __syncthreads();
        const int k0 = kt * 128;
#pragma unroll
        for (int h = 0; h < 4; ++h) {
            const int r = wave * 32 + h * 8 + sRow;     // tile row 0..127
            const unsigned char* ga = A + (size_t)(rowBase + r) * d + k0 + srcOffC;
            const unsigned char* gb = A + (size_t)(colBase + r) * d + k0 + srcOffC;
            __builtin_amdgcn_global_load_lds(
                (const __attribute__((address_space(1))) void*)ga,
                (__attribute__((address_space(3))) void*)(ldsA + r * 128 + sChk * 16), 16, 0, 0);
            __builtin_amdgcn_global_load_lds(
                (const __attribute__((address_space(1))) void*)gb,
                (__attribute__((address_space(3))) void*)(ldsB + r * 128 + sChk * 16), 16, 0, 0);
        }
        __syncthreads();

#pragma unroll
        for (int ko = 0; ko < 4; ++ko) {
            const int koff = ((2 * ko + fragChkBase) ^ rx) * 16 + fragOddB;
            f8x8 af[4], bf[4];
#pragma unroll
            for (int t4 = 0; t4 < 4; ++t4) {
                const int ra = wr + t4 * 16 + rl;
                const int rb = wc + t4 * 16 + rl;
                af[t4] = *(const f8x8*)(ldsA + ra * 128 + koff);
                bf[t4] = *(const f8x8*)(ldsB + rb * 128 + koff);
            }
#pragma unroll
            for (int rt = 0; rt < 4; ++rt)
#pragma unroll
                for (int ct = 0; ct < 4; ++ct)
                    acc[rt][ct] = __builtin_amdgcn_mfma_f32_16x16x32_fp8_fp8(
                        af[rt], bf[ct], acc[rt][ct], 0, 0, 0);
        }
    }

    // ---- epilogue (16x16 C/D: col=lane&15, row=(lane>>4)*4+reg) ----
    const int q  = lane >> 4;
    const int jlo = colBase + wc;
    const int ilo = rowBase + wr;

    int   jn[4];
    float jinv[4];
    bool  jvalid[4];
#pragma unroll
    for (int ct = 0; ct < 4; ++ct) {
        const int j = jlo + ct * 16 + rl;
        jn[ct]  = j;
        jinv[ct] = inv_norm[j];
        jvalid[ct] = (j < M);
    }

    // wave-uniform positive-pair possibility check
    bool posLane = false;
    {
        const int ri = ilo + lane;
        if (ri < M) posLane |= (ends[ri] >= jlo) && (starts[ri] <= jlo + 63);
        if (!isDiag) {
            const int cj = jlo + lane;
            if (cj < M) posLane |= (ends[cj] >= ilo) && (starts[cj] <= ilo + 63);
        }
    }
    const bool fullPath = (__ballot(posLane) != 0ULL);

    float posc[4] = {0.f, 0.f, 0.f, 0.f};
    float negc[4] = {0.f, 0.f, 0.f, 0.f};

    if (fullPath) {
        int   jns[4], jne[4];
        float jsq[4];
#pragma unroll
        for (int ct = 0; ct < 4; ++ct) {
            jsq[ct] = sq[jn[ct]];
            jns[ct] = jvalid[ct] ? starts[jn[ct]] : 0;
            jne[ct] = jvalid[ct] ? ends[jn[ct]]   : -1;
        }
#pragma unroll
        for (int rt = 0; rt < 4; ++rt) {
            const int ibase = ilo + rt * 16 + q * 4;
#pragma unroll
            for (int reg = 0; reg < 4; ++reg) {
                const int i = ibase + reg;
                const bool rowValid = (i < M);
                const int ns = rowValid ? starts[i] : 0;
                const int ne = rowValid ? ends[i]   : -1;
                const float iinv = inv_norm[i];
                const float isq  = sq[i];
                float posp = 0.f, negp = 0.f;
#pragma unroll
                for (int ct = 0; ct < 4; ++ct) {
                    const float dot = acc[rt][ct][reg];
                    const int j = jn[ct];
                    float cosv = dot * iinv * jinv[ct];
                    cosv = fminf(fmaxf(cosv, -1.f), 1.f);
                    float tn = fmaxf(fabsf(cosv) - M_NEG, 0.f);
                    const float nterm = tn * tn;
                    const float d2 = fmaxf(isq + jsq[ct] - 2.f * dot, 0.f);
                    float tp = fmaxf(sqrtf(d2) - M_POS, 0.f);
                    const float pterm = tp * tp;
                    const bool dg = (j == i);
                    if (rowValid) {
                        const bool in_r = (j >= ns) && (j <= ne);
                        if (in_r && !dg) posp += pterm;
                        if (!in_r || dg) negp += nterm;
                    }
                    if (!isDiag && jvalid[ct]) {
                        const bool in_c = (i >= jns[ct]) && (i <= jne[ct]);
                        if (in_c && !dg) posc[ct] += pterm;
                        if (!in_c || dg) negc[ct] += nterm;
                    }
                }
#pragma unroll
                for (int m = 1; m < 16; m <<= 1) {
                    posp += __shfl_xor(posp, m, 64);
                    negp += __shfl_xor(negp, m, 64);
                }
                if (rowValid && rl == 0) {
                    atomicAdd(&pos_acc[i], posp);
                    atomicAdd(&neg_acc[i], negp);
                }
            }
        }
        if (!isDiag) {
#pragma unroll
            for (int ct = 0; ct < 4; ++ct) {
                posc[ct] += __shfl_xor(posc[ct], 16, 64);
                posc[ct] += __shfl_xor(posc[ct], 32, 64);
                negc[ct] += __shfl_xor(negc[ct], 16, 64);
                negc[ct] += __shfl_xor(negc[ct], 32, 64);
            }
            if (q == 0) {
#pragma unroll
                for (int ct = 0; ct < 4; ++ct) {
                    if (jvalid[ct]) {
                        atomicAdd(&pos_acc[jn[ct]], posc[ct]);
                        atomicAdd(&neg_acc[jn[ct]], negc[ct]);
                    }
                }
            }
        }
    } else {
        // fast path: every element is a negative for both its row and its column
#pragma unroll
        for (int rt = 0; rt < 4; ++rt) {
            const int ibase = ilo + rt * 16 + q * 4;
#pragma unroll
            for (int reg = 0; reg < 4; ++reg) {
                const int i = ibase + reg;
                const float iinv = inv_norm[i];
                float negp = 0.f;
#pragma unroll
                for (int ct = 0; ct < 4; ++ct) {
                    const float dot = acc[rt][ct][reg];
                    float cosv = dot * iinv * jinv[ct];
                    cosv = fminf(fmaxf(cosv, -1.f), 1.f);
                    float tn = fmaxf(fabsf(cosv) - M_NEG, 0.f);
                    const float nterm = tn * tn;
                    negp += nterm;
                    negc[ct] += nterm;
                }
#pragma unroll
                for (int m = 1; m < 16; m <<= 1)
                    negp += __shfl_xor(negp, m, 64);
                if ((i < M) && rl == 0)
                    atomicAdd(&neg_acc[i], negp);
            }
        }
        if (!isDiag) {
#pragma unroll
            for (int ct = 0; ct < 4; ++ct) {
                negc[ct] += __shfl_xor(negc[ct], 16, 64);
                negc[ct] += __shfl_xor(negc[ct], 32, 64);
            }
            if (q == 0) {
#pragma unroll
                for (int ct = 0; ct < 4; ++ct)
                    if (jvalid[ct])
                        atomicAdd(&neg_acc[jn[ct]], negc[ct]);
            }
        }
    }

    // ---- last-block finalize (fence/atomic by tid0 only — NOT per-thread like R3) ----
    __shared__ bool amLast;
    __syncthreads();                       // drains this block's atomics (vmcnt 0)
    if (tid == 0) {
        __threadfence();
        unsigned old = atomicAdd(counter, 1u);
        amLast = (old == (unsigned)(gridDim.x - 1));
    }
    __syncthreads();
    if (amLast) {
        __threadfence();
        float total = 0.f;
        int cnt = 0;
        for (int i = tid; i < M; i += 256) {
            const float pa = __hip_atomic_load(&pos_acc[i], __ATOMIC_RELAXED, __HIP_MEMORY_SCOPE_AGENT);
            const float na = __hip_atomic_load(&neg_acc[i], __ATOMIC_RELAXED, __HIP_MEMORY_SCOPE_AGENT);
            const int ns = starts[i], ne = ends[i];
            const int lo = max(ns, 0), hi = min(ne, N - 1);
            const int inr = max(hi - lo + 1, 0);
            const bool dg = (i >= ns) && (i <= ne);
            const int pos_cnt = inr - (dg ? 1 : 0);
            const int neg_cnt = N - inr + (dg ? 1 : 0);
            if (pos_cnt > 0 && neg_cnt > 0) {
                total += pa / (float)max(pos_cnt, 1)
                       + LAM_NEG * na / (float)max(neg_cnt, 1);
                cnt++;
            }
        }
        for (int o = 32; o > 0; o >>= 1) {
            total += __shfl_down(total, o, 64);
            cnt   += __shfl_down(cnt, o, 64);
        }
        __shared__ float fin_ts[4];
        __shared__ int   fin_cs[4];
        if ((tid & 63) == 0) { fin_ts[tid >> 6] = total; fin_cs[tid >> 6] = cnt; }
        __syncthreads();
        if (tid == 0) {
            float T = fin_ts[0] + fin_ts[1] + fin_ts[2] + fin_ts[3];
            int   C = fin_cs[0] + fin_cs[1] + fin_cs[2] + fin_cs[3];
            out[0] = (C > 0) ? T / (float)C : 0.f;
        }
    }
}

extern "C" void kernel_launch(void* const* d_in, const int* in_sizes, int n_in,
                              void* d_out, int out_size, void* d_ws, size_t ws_size,
                              hipStream_t stream) {
    const float* cb     = (const float*)d_in[0];
    const int*   starts = (const int*)d_in[1];
    const int*   ends   = (const int*)d_in[2];
    const int*   max_ip = (const int*)d_in[3];
    float* out = (float*)d_out;

    const int N = in_sizes[1];
    const int d = in_sizes[0] / N;

    char* ws = (char*)d_ws;
    unsigned char* cb_q = (unsigned char*)ws;
    size_t off = ((size_t)N * d + 255) & ~(size_t)255;
    float* sq       = (float*)(ws + off); off += (size_t)N * 4;
    float* inv_norm = (float*)(ws + off); off += (size_t)N * 4;
    float* pos_acc  = (float*)(ws + off); off += (size_t)N * 4;
    float* neg_acc  = (float*)(ws + off); off += (size_t)N * 4;
    unsigned* counter = (unsigned*)(ws + off); off += 256;

    // prep zeroes pos_acc/neg_acc/counter (2N+1 u32, contiguous)
    prep_kernel<<<N, 256, 0, stream>>>(cb, cb_q, sq, inv_norm,
                                       (unsigned*)pos_acc, 2 * N + 1, N, d);

    const int nb = N / 128;
    const int nBlocks = nb * (nb + 1) / 2;   // upper-triangular tiles
    gram_loss_kernel<<<nBlocks, 256, 0, stream>>>(cb_q, sq, inv_norm, starts, ends,
                                                  max_ip, pos_acc, neg_acc, counter,
                                                  out, N, d);
}

// Round 8
// 201.595 us; speedup vs baseline: 1.1290x; 1.0566x over previous
//
#include <hip/hip_runtime.h>
#include <hip/hip_bf16.h>
#include <stdint.h>

#define M_POS 0.5f
#define M_NEG 0.1f
#define LAM_NEG 1.0f

typedef __attribute__((ext_vector_type(4))) float floatx4;  // 16x16 MFMA accumulator
typedef __attribute__((ext_vector_type(8))) int   intx8;    // 32B fp8 operand (K=128)

union Frag8 { intx8 v; int4 q[2]; };

// ---------------- Kernel A: row sumsq, inv_norm, fp32 -> fp8(e4m3) quantize, zero accs ----
__global__ __launch_bounds__(256) void prep_kernel(
    const float* __restrict__ cb, unsigned char* __restrict__ cb_q,
    float* __restrict__ sq, float* __restrict__ inv_norm,
    unsigned* __restrict__ zero_base, int zero_len,
    int N, int d)
{
    const int gi = blockIdx.x * 256 + threadIdx.x;
    if (gi < zero_len) zero_base[gi] = 0u;

    const int row = blockIdx.x;
    const float* src = cb + (size_t)row * d;
    unsigned char* dst = cb_q + (size_t)row * d;
    const int t = threadIdx.x;

    float s = 0.f;
    for (int c = t * 4; c < d; c += 1024) {
        float4 v = *(const float4*)(src + c);
        s += v.x * v.x + v.y * v.y + v.z * v.z + v.w * v.w;
        int pk = __builtin_amdgcn_cvt_pk_fp8_f32(v.x, v.y, 0, false);   // bytes 0,1
        pk     = __builtin_amdgcn_cvt_pk_fp8_f32(v.z, v.w, pk, true);   // bytes 2,3
        *(int*)(dst + c) = pk;
    }
    for (int o = 32; o > 0; o >>= 1) s += __shfl_down(s, o, 64);
    __shared__ float wsum[4];
    if ((t & 63) == 0) wsum[t >> 6] = s;
    __syncthreads();
    if (t == 0) {
        float tot = wsum[0] + wsum[1] + wsum[2] + wsum[3];
        sq[row] = tot;
        inv_norm[row] = rsqrtf(tot);
    }
}

// ---------------- Kernel B: fused symmetric MX-fp8 Gram GEMM + loss epilogue + finalize ----
// R7 BK=128 layout, but inner loop is v_mfma_scale_f32_16x16x128_f8f6f4 with unit E8M0
// scales (127 = 2^0) — bit-identical to non-scaled fp8 at 2x MFMA rate (m148 rung).
// Per kt: each of 16 acc tiles takes ONE K=128 MFMA (16 independent MFMAs — ILP kept,
// unlike R6's 32x32x64 failure). Fragment reads: 2x ds_read_b128 per operand, XOR
// swizzle (chunk' = chunk ^ (row&7)) -> 8 words/bank = b128 conflict-free floor.
// Last-block finalize with tid0-only fence (validated R7).
__global__ __launch_bounds__(256, 3) void gram_loss_kernel(
    const unsigned char* __restrict__ A,   // N x d fp8
    const float* __restrict__ sq, const float* __restrict__ inv_norm,
    const int* __restrict__ starts, const int* __restrict__ ends,
    const int* __restrict__ max_ip,
    float* __restrict__ pos_acc, float* __restrict__ neg_acc,
    unsigned* __restrict__ counter, float* __restrict__ out,
    int N, int d)
{
    const int M = min(N, max_ip[0] + 1);

    // triangular decode: blockIdx.x -> (by, bx), by <= bx
    const int t = blockIdx.x;
    int bx = (int)((sqrtf(8.f * (float)t + 1.f) - 1.f) * 0.5f);
    while ((bx + 1) * (bx + 2) / 2 <= t) bx++;
    while (bx * (bx + 1) / 2 > t) bx--;
    const int by = t - bx * (bx + 1) / 2;

    const int rowBase = by * 128;
    const int colBase = bx * 128;
    const bool isDiag = (by == bx);

    __shared__ alignas(16) unsigned char ldsA[128 * 128];
    __shared__ alignas(16) unsigned char ldsB[128 * 128];

    const int tid  = threadIdx.x;
    const int wave = tid >> 6;
    const int lane = tid & 63;
    const int wr = (wave >> 1) * 64;
    const int wc = (wave & 1) * 64;

    floatx4 acc[4][4];
#pragma unroll
    for (int a = 0; a < 4; ++a)
#pragma unroll
        for (int b = 0; b < 4; ++b) acc[a][b] = (floatx4){0.f, 0.f, 0.f, 0.f};

    // staging: per issue, 8 rows x 8 chunks; dst lane-linear; src chunk xor lane-constant.
    const int sRow = lane >> 3;                         // 0..7
    const int sChk = lane & 7;                          // 16B chunk 0..7
    const int srcOffC = ((sChk ^ sRow) * 16);
    const int kTiles = d / 128;                         // 8

    // fragment-read constants: lane holds k = (lane>>4)*32 .. +31 of its row
    const int rl = lane & 15;
    const int g  = lane >> 4;       // 0..3 (k-group)
    const int rx = rl & 7;
    const int c0 = (((2 * g)     ^ rx) * 16);
    const int c1 = (((2 * g + 1) ^ rx) * 16);

    for (int kt = 0; kt < kTiles; ++kt) {
        __syncthreads();
        const int k0 = kt * 128;
#pragma unroll
        for (int h = 0; h < 4; ++h) {
            const int r = wave * 32 + h * 8 + sRow;     // tile row 0..127
            const unsigned char* ga = A + (size_t)(rowBase + r) * d + k0 + srcOffC;
            const unsigned char* gb = A + (size_t)(colBase + r) * d + k0 + srcOffC;
            __builtin_amdgcn_global_load_lds(
                (const __attribute__((address_space(1))) void*)ga,
                (__attribute__((address_space(3))) void*)(ldsA + r * 128 + sChk * 16), 16, 0, 0);
            __builtin_amdgcn_global_load_lds(
                (const __attribute__((address_space(1))) void*)gb,
                (__attribute__((address_space(3))) void*)(ldsB + r * 128 + sChk * 16), 16, 0, 0);
        }
        __syncthreads();

        Frag8 af[4], bf[4];
#pragma unroll
        for (int t4 = 0; t4 < 4; ++t4) {
            const unsigned char* pa = ldsA + (wr + t4 * 16 + rl) * 128;
            af[t4].q[0] = *(const int4*)(pa + c0);
            af[t4].q[1] = *(const int4*)(pa + c1);
            const unsigned char* pb = ldsB + (wc + t4 * 16 + rl) * 128;
            bf[t4].q[0] = *(const int4*)(pb + c0);
            bf[t4].q[1] = *(const int4*)(pb + c1);
        }
#pragma unroll
        for (int rt = 0; rt < 4; ++rt)
#pragma unroll
            for (int ct = 0; ct < 4; ++ct)
                acc[rt][ct] = __builtin_amdgcn_mfma_scale_f32_16x16x128_f8f6f4(
                    af[rt].v, bf[ct].v, acc[rt][ct], 0, 0, 0, 127, 0, 127);
    }

    // ---- epilogue (16x16 C/D: col=lane&15, row=(lane>>4)*4+reg) ----
    const int q  = lane >> 4;
    const int jlo = colBase + wc;
    const int ilo = rowBase + wr;

    int   jn[4];
    float jinv[4];
    bool  jvalid[4];
#pragma unroll
    for (int ct = 0; ct < 4; ++ct) {
        const int j = jlo + ct * 16 + rl;
        jn[ct]  = j;
        jinv[ct] = inv_norm[j];
        jvalid[ct] = (j < M);
    }

    // wave-uniform positive-pair possibility check
    bool posLane = false;
    {
        const int ri = ilo + lane;
        if (ri < M) posLane |= (ends[ri] >= jlo) && (starts[ri] <= jlo + 63);
        if (!isDiag) {
            const int cj = jlo + lane;
            if (cj < M) posLane |= (ends[cj] >= ilo) && (starts[cj] <= ilo + 63);
        }
    }
    const bool fullPath = (__ballot(posLane) != 0ULL);

    float posc[4] = {0.f, 0.f, 0.f, 0.f};
    float negc[4] = {0.f, 0.f, 0.f, 0.f};

    if (fullPath) {
        int   jns[4], jne[4];
        float jsq[4];
#pragma unroll
        for (int ct = 0; ct < 4; ++ct) {
            jsq[ct] = sq[jn[ct]];
            jns[ct] = jvalid[ct] ? starts[jn[ct]] : 0;
            jne[ct] = jvalid[ct] ? ends[jn[ct]]   : -1;
        }
#pragma unroll
        for (int rt = 0; rt < 4; ++rt) {
            const int ibase = ilo + rt * 16 + q * 4;
#pragma unroll
            for (int reg = 0; reg < 4; ++reg) {
                const int i = ibase + reg;
                const bool rowValid = (i < M);
                const int ns = rowValid ? starts[i] : 0;
                const int ne = rowValid ? ends[i]   : -1;
                const float iinv = inv_norm[i];
                const float isq  = sq[i];
                float posp = 0.f, negp = 0.f;
#pragma unroll
                for (int ct = 0; ct < 4; ++ct) {
                    const float dot = acc[rt][ct][reg];
                    const int j = jn[ct];
                    float cosv = dot * iinv * jinv[ct];
                    cosv = fminf(fmaxf(cosv, -1.f), 1.f);
                    float tn = fmaxf(fabsf(cosv) - M_NEG, 0.f);
                    const float nterm = tn * tn;
                    const float d2 = fmaxf(isq + jsq[ct] - 2.f * dot, 0.f);
                    float tp = fmaxf(sqrtf(d2) - M_POS, 0.f);
                    const float pterm = tp * tp;
                    const bool dg = (j == i);
                    if (rowValid) {
                        const bool in_r = (j >= ns) && (j <= ne);
                        if (in_r && !dg) posp += pterm;
                        if (!in_r || dg) negp += nterm;
                    }
                    if (!isDiag && jvalid[ct]) {
                        const bool in_c = (i >= jns[ct]) && (i <= jne[ct]);
                        if (in_c && !dg) posc[ct] += pterm;
                        if (!in_c || dg) negc[ct] += nterm;
                    }
                }
#pragma unroll
                for (int m = 1; m < 16; m <<= 1) {
                    posp += __shfl_xor(posp, m, 64);
                    negp += __shfl_xor(negp, m, 64);
                }
                if (rowValid && rl == 0) {
                    atomicAdd(&pos_acc[i], posp);
                    atomicAdd(&neg_acc[i], negp);
                }
            }
        }
        if (!isDiag) {
#pragma unroll
            for (int ct = 0; ct < 4; ++ct) {
                posc[ct] += __shfl_xor(posc[ct], 16, 64);
                posc[ct] += __shfl_xor(posc[ct], 32, 64);
                negc[ct] += __shfl_xor(negc[ct], 16, 64);
                negc[ct] += __shfl_xor(negc[ct], 32, 64);
            }
            if (q == 0) {
#pragma unroll
                for (int ct = 0; ct < 4; ++ct) {
                    if (jvalid[ct]) {
                        atomicAdd(&pos_acc[jn[ct]], posc[ct]);
                        atomicAdd(&neg_acc[jn[ct]], negc[ct]);
                    }
                }
            }
        }
    } else {
        // fast path: every element is a negative for both its row and its column
#pragma unroll
        for (int rt = 0; rt < 4; ++rt) {
            const int ibase = ilo + rt * 16 + q * 4;
#pragma unroll
            for (int reg = 0; reg < 4; ++reg) {
                const int i = ibase + reg;
                const float iinv = inv_norm[i];
                float negp = 0.f;
#pragma unroll
                for (int ct = 0; ct < 4; ++ct) {
                    const float dot = acc[rt][ct][reg];
                    float cosv = dot * iinv * jinv[ct];
                    cosv = fminf(fmaxf(cosv, -1.f), 1.f);
                    float tn = fmaxf(fabsf(cosv) - M_NEG, 0.f);
                    const float nterm = tn * tn;
                    negp += nterm;
                    negc[ct] += nterm;
                }
#pragma unroll
                for (int m = 1; m < 16; m <<= 1)
                    negp += __shfl_xor(negp, m, 64);
                if ((i < M) && rl == 0)
                    atomicAdd(&neg_acc[i], negp);
            }
        }
        if (!isDiag) {
#pragma unroll
            for (int ct = 0; ct < 4; ++ct) {
                negc[ct] += __shfl_xor(negc[ct], 16, 64);
                negc[ct] += __shfl_xor(negc[ct], 32, 64);
            }
            if (q == 0) {
#pragma unroll
                for (int ct = 0; ct < 4; ++ct)
                    if (jvalid[ct])
                        atomicAdd(&neg_acc[jn[ct]], negc[ct]);
            }
        }
    }

    // ---- last-block finalize (fence/atomic by tid0 only — validated R7) ----
    __shared__ bool amLast;
    __syncthreads();
    if (tid == 0) {
        __threadfence();
        unsigned old = atomicAdd(counter, 1u);
        amLast = (old == (unsigned)(gridDim.x - 1));
    }
    __syncthreads();
    if (amLast) {
        __threadfence();
        float total = 0.f;
        int cnt = 0;
        for (int i = tid; i < M; i += 256) {
            const float pa = __hip_atomic_load(&pos_acc[i], __ATOMIC_RELAXED, __HIP_MEMORY_SCOPE_AGENT);
            const float na = __hip_atomic_load(&neg_acc[i], __ATOMIC_RELAXED, __HIP_MEMORY_SCOPE_AGENT);
            const int ns = starts[i], ne = ends[i];
            const int lo = max(ns, 0), hi = min(ne, N - 1);
            const int inr = max(hi - lo + 1, 0);
            const bool dg = (i >= ns) && (i <= ne);
            const int pos_cnt = inr - (dg ? 1 : 0);
            const int neg_cnt = N - inr + (dg ? 1 : 0);
            if (pos_cnt > 0 && neg_cnt > 0) {
                total += pa / (float)max(pos_cnt, 1)
                       + LAM_NEG * na / (float)max(neg_cnt, 1);
                cnt++;
            }
        }
        for (int o = 32; o > 0; o >>= 1) {
            total += __shfl_down(total, o, 64);
            cnt   += __shfl_down(cnt, o, 64);
        }
        __shared__ float fin_ts[4];
        __shared__ int   fin_cs[4];
        if ((tid & 63) == 0) { fin_ts[tid >> 6] = total; fin_cs[tid >> 6] = cnt; }
        __syncthreads();
        if (tid == 0) {
            float T = fin_ts[0] + fin_ts[1] + fin_ts[2] + fin_ts[3];
            int   C = fin_cs[0] + fin_cs[1] + fin_cs[2] + fin_cs[3];
            out[0] = (C > 0) ? T / (float)C : 0.f;
        }
    }
}

extern "C" void kernel_launch(void* const* d_in, const int* in_sizes, int n_in,
                              void* d_out, int out_size, void* d_ws, size_t ws_size,
                              hipStream_t stream) {
    const float* cb     = (const float*)d_in[0];
    const int*   starts = (const int*)d_in[1];
    const int*   ends   = (const int*)d_in[2];
    const int*   max_ip = (const int*)d_in[3];
    float* out = (float*)d_out;

    const int N = in_sizes[1];
    const int d = in_sizes[0] / N;

    char* ws = (char*)d_ws;
    unsigned char* cb_q = (unsigned char*)ws;
    size_t off = ((size_t)N * d + 255) & ~(size_t)255;
    float* sq       = (float*)(ws + off); off += (size_t)N * 4;
    float* inv_norm = (float*)(ws + off); off += (size_t)N * 4;
    float* pos_acc  = (float*)(ws + off); off += (size_t)N * 4;
    float* neg_acc  = (float*)(ws + off); off += (size_t)N * 4;
    unsigned* counter = (unsigned*)(ws + off); off += 256;

    // prep zeroes pos_acc/neg_acc/counter (2N+1 u32, contiguous)
    prep_kernel<<<N, 256, 0, stream>>>(cb, cb_q, sq, inv_norm,
                                       (unsigned*)pos_acc, 2 * N + 1, N, d);

    const int nb = N / 128;
    const int nBlocks = nb * (nb + 1) / 2;   // upper-triangular tiles
    gram_loss_kernel<<<nBlocks, 256, 0, stream>>>(cb_q, sq, inv_norm, starts, ends,
                                                  max_ip, pos_acc, neg_acc, counter,
                                                  out, N, d);
}